// Round 1
// baseline (334.731 us; speedup 1.0000x reference)
//
#include <hip/hip_runtime.h>
#include <hip/hip_bf16.h>

// EdgewiseReduce: out[n, :] = sum_{e : dst[e]==n} edge_data[e, :] * 0.5
// E = 1.6M, D = 32, N = 100K.
//
// History:
//  R1: 51.2M f32 global atomics -> 819 MB of 16B txns, 647 us.
//  R2: full counting sort; random 4B scatter -> 106 MB line writebacks, 494.
//  R3: replicated scan -> 1.6 GB L3 traffic, 378 us.
//  R4-R6: LDS-atomic gather stuck 340-464 us (compiler won't pipeline
//         global loads across LDS atomics; VGPR pinned at 32).
//  R7: register-accumulating gather + in-LDS bucket sort -> 352 us total.
//  R8: fixed-capacity buckets (cap=4096/bucket) -> 329.7 us.
//  R9 (this): balanced gather consume. Per-node ownership made wave time
//     ~ max of 16 Poisson(16) counts (~1.6x mean). Now each 4-lane group
//     consumes exactly ceil(cnt/128) consecutive SORTED entries; run
//     boundaries are known from the scan (j+1 == end[node]), partial runs
//     flush via 8 LDS float atomics into a per-node accumulator that
//     reuses the ids[] LDS (dead after sort). Uniform trip count => all
//     groups take the 4-unrolled high-ILP path, no Poisson tail.

#define D 32
#define FACTOR 0.5f
#define BSHIFT 7                 // 128 nodes per bucket
#define BNODES (1 << BSHIFT)
#define CAPSHIFT 12              // 4096 slots per bucket
#define CAP (1 << CAPSHIFT)

// ---------- K0: init cursors + overflow count ----------
__global__ void init_kernel(int* __restrict__ cursor, int* __restrict__ ovf_count,
                            int nb) {
  int i = blockIdx.x * blockDim.x + threadIdx.x;
  if (i == 0) *ovf_count = 0;
  if (i < nb) cursor[i] = i << CAPSHIFT;
}

// ---------- K1: per-block reserve + scatter packed ids (128 blocks) ----------
__global__ void scatter_kernel(const int* __restrict__ dst, int* __restrict__ gcursor,
                               int* __restrict__ order, int2* __restrict__ ovf,
                               int* __restrict__ ovf_count, int E, int N, int nb,
                               int chunk) {
  extern __shared__ int sm[];
  int* lhist = sm;            // [nb]
  int* lcur = sm + nb;        // [nb]
  int lo = blockIdx.x * chunk;          // chunk is 4-aligned
  int hiE = min(lo + chunk, E);
  const int4* dst4 = (const int4*)dst;

  for (int i = threadIdx.x; i < nb; i += blockDim.x) lhist[i] = 0;
  __syncthreads();

  int lo4 = lo >> 2;
  int full4 = (hiE - lo) >> 2;
  for (int i = threadIdx.x; i < full4; i += blockDim.x) {
    int4 v = dst4[lo4 + i];
    if ((unsigned)v.x < (unsigned)N) atomicAdd(&lhist[v.x >> BSHIFT], 1);
    if ((unsigned)v.y < (unsigned)N) atomicAdd(&lhist[v.y >> BSHIFT], 1);
    if ((unsigned)v.z < (unsigned)N) atomicAdd(&lhist[v.z >> BSHIFT], 1);
    if ((unsigned)v.w < (unsigned)N) atomicAdd(&lhist[v.w >> BSHIFT], 1);
  }
  int tb = lo + (full4 << 2) + threadIdx.x;
  if (tb < hiE) {
    int d = dst[tb];
    if ((unsigned)d < (unsigned)N) atomicAdd(&lhist[d >> BSHIFT], 1);
  }
  __syncthreads();

  for (int i = threadIdx.x; i < nb; i += blockDim.x) {
    int c = lhist[i];
    lcur[i] = c ? atomicAdd(&gcursor[i], c) : 0;   // global positions
  }
  __syncthreads();

  #define EMIT(dd, ee)                                                        \
    if ((unsigned)(dd) < (unsigned)N) {                                       \
      int bkt = (dd) >> BSHIFT;                                               \
      int pos = atomicAdd(&lcur[bkt], 1);                                     \
      if (pos < ((bkt + 1) << CAPSHIFT)) {                                    \
        order[pos] = ((ee) << BSHIFT) | ((dd) & (BNODES - 1));                \
      } else {                                                                \
        int op = atomicAdd(ovf_count, 1);                                     \
        ovf[op] = make_int2((ee), (dd));                                      \
      }                                                                       \
    }

  for (int i = threadIdx.x; i < full4; i += blockDim.x) {
    int e = lo + (i << 2);
    int4 v = dst4[lo4 + i];
    EMIT(v.x, e + 0)
    EMIT(v.y, e + 1)
    EMIT(v.z, e + 2)
    EMIT(v.w, e + 3)
  }
  if (tb < hiE) {
    int d = dst[tb];
    EMIT(d, tb)
  }
  #undef EMIT
}

// ---------- K2: gather-reduce, balanced consume over sorted list ----------
// 512 threads = 128 groups x 4 lanes. Phases:
//   stage+hist -> 1-wave scan -> LDS counting sort -> zero acc (reuses ids)
//   -> balanced consume (group g takes sorted[g*W, g*W+W)) -> write out.
#define K4_THREADS 512
__global__ __launch_bounds__(K4_THREADS)
void gather_kernel(const float4* __restrict__ data, const int* __restrict__ order,
                   const int* __restrict__ cursor, float4* __restrict__ out,
                   int N) {
  __shared__ int sorted[CAP];      // node-sorted ids (16 KB)
  __shared__ int ids[CAP];         // staged ids; reused as float acc[128][32]
  __shared__ int hist[BNODES];
  __shared__ int endo[BNODES];     // exclusive end of each node's run
  __shared__ int cur[BNODES];      // scatter cursors (mutated)

  const int b = blockIdx.x;
  const int base = b << CAPSHIFT;
  int cnt = cursor[b] - base;
  if (cnt > CAP) cnt = CAP;        // overflow handled by overflow_kernel
  if (cnt < 0) cnt = 0;
  const int lo = b << BSHIFT;
  const int tid = threadIdx.x;
  const int grp = tid >> 2;        // group id 0..127
  const int ln = tid & 3;          // 32B slice within the 128B row

  for (int i = tid; i < BNODES; i += K4_THREADS) hist[i] = 0;
  __syncthreads();
  for (int i = tid; i < cnt; i += K4_THREADS) {
    int v = order[base + i];
    ids[i] = v;
    atomicAdd(&hist[v & (BNODES - 1)], 1);
  }
  __syncthreads();

  // Single-wave inclusive scan over 128 counters (lane l owns 2l, 2l+1).
  if (tid < 64) {
    int c0 = hist[2 * tid], c1 = hist[2 * tid + 1];
    int s = c0 + c1;
    int sc = s;
    #pragma unroll
    for (int off = 1; off < 64; off <<= 1) {
      int t = __shfl_up(sc, off);
      if (tid >= off) sc += t;
    }
    int bs = sc - s;                 // exclusive base for node 2*tid
    endo[2 * tid] = bs + c0;         // exclusive end of node 2*tid's run
    endo[2 * tid + 1] = bs + c0 + c1;
    cur[2 * tid] = bs;
    cur[2 * tid + 1] = bs + c0;
  }
  __syncthreads();

  for (int i = tid; i < cnt; i += K4_THREADS) {
    int v = ids[i];
    sorted[atomicAdd(&cur[v & (BNODES - 1)], 1)] = v;
  }
  __syncthreads();

  // ids[] is dead; reuse as per-node accumulator acc[128][32] f32.
  float* accf = (float*)ids;
  for (int i = tid; i < BNODES * D; i += K4_THREADS) accf[i] = 0.f;
  __syncthreads();

  // Balanced consume: group g takes exactly W consecutive sorted entries.
  const int W = (cnt + BNODES - 1) >> BSHIFT;
  const int i0 = grp * W;
  const int i1 = min(i0 + W, cnt);

  float4 a0 = make_float4(0.f, 0.f, 0.f, 0.f);
  float4 a1 = make_float4(0.f, 0.f, 0.f, 0.f);

  #define FLUSH(nd)                                                           \
    {                                                                         \
      float* fp = accf + ((nd) << 5) + (ln << 3);                             \
      atomicAdd(fp + 0, a0.x); atomicAdd(fp + 1, a0.y);                       \
      atomicAdd(fp + 2, a0.z); atomicAdd(fp + 3, a0.w);                       \
      atomicAdd(fp + 4, a1.x); atomicAdd(fp + 5, a1.y);                       \
      atomicAdd(fp + 6, a1.z); atomicAdd(fp + 7, a1.w);                       \
      a0 = make_float4(0.f, 0.f, 0.f, 0.f);                                   \
      a1 = make_float4(0.f, 0.f, 0.f, 0.f);                                   \
    }

  int j = i0;
  for (; j + 3 < i1; j += 4) {
    int v0 = sorted[j], v1 = sorted[j + 1], v2 = sorted[j + 2], v3 = sorted[j + 3];
    const float4* p0 = data + (size_t)(v0 >> BSHIFT) * 8 + ln * 2;
    const float4* p1 = data + (size_t)(v1 >> BSHIFT) * 8 + ln * 2;
    const float4* p2 = data + (size_t)(v2 >> BSHIFT) * 8 + ln * 2;
    const float4* p3 = data + (size_t)(v3 >> BSHIFT) * 8 + ln * 2;
    float4 x0 = p0[0], y0 = p0[1];
    float4 x1 = p1[0], y1 = p1[1];
    float4 x2 = p2[0], y2 = p2[1];
    float4 x3 = p3[0], y3 = p3[1];
    a0.x += x0.x; a0.y += x0.y; a0.z += x0.z; a0.w += x0.w;
    a1.x += y0.x; a1.y += y0.y; a1.z += y0.z; a1.w += y0.w;
    { int nd = v0 & (BNODES - 1); if (j + 1 == endo[nd]) FLUSH(nd); }
    a0.x += x1.x; a0.y += x1.y; a0.z += x1.z; a0.w += x1.w;
    a1.x += y1.x; a1.y += y1.y; a1.z += y1.z; a1.w += y1.w;
    { int nd = v1 & (BNODES - 1); if (j + 2 == endo[nd]) FLUSH(nd); }
    a0.x += x2.x; a0.y += x2.y; a0.z += x2.z; a0.w += x2.w;
    a1.x += y2.x; a1.y += y2.y; a1.z += y2.z; a1.w += y2.w;
    { int nd = v2 & (BNODES - 1); if (j + 3 == endo[nd]) FLUSH(nd); }
    a0.x += x3.x; a0.y += x3.y; a0.z += x3.z; a0.w += x3.w;
    a1.x += y3.x; a1.y += y3.y; a1.z += y3.z; a1.w += y3.w;
    { int nd = v3 & (BNODES - 1); if (j + 4 == endo[nd]) FLUSH(nd); }
  }
  for (; j < i1; ++j) {
    int v = sorted[j];
    const float4* p = data + (size_t)(v >> BSHIFT) * 8 + ln * 2;
    float4 x = p[0], y = p[1];
    a0.x += x.x; a0.y += x.y; a0.z += x.z; a0.w += x.w;
    a1.x += y.x; a1.y += y.y; a1.z += y.z; a1.w += y.w;
    { int nd = v & (BNODES - 1); if (j + 1 == endo[nd]) FLUSH(nd); }
  }
  // Partial run crossing the window end: flush whatever remains.
  if (i1 > i0) {
    int nd = sorted[i1 - 1] & (BNODES - 1);
    if (i1 != endo[nd]) FLUSH(nd);
  }
  #undef FLUSH
  __syncthreads();

  // Write out: 1024 float4 per block, fully coalesced, conflict-free LDS.
  const float4* accv = (const float4*)accf;
  for (int i = tid; i < (BNODES * D) / 4; i += K4_THREADS) {
    int node = lo + (i >> 3);
    if (node < N) {
      float4 v = accv[i];
      v.x *= FACTOR; v.y *= FACTOR; v.z *= FACTOR; v.w *= FACTOR;
      out[(size_t)node * 8 + (i & 7)] = v;
    }
  }
}

// ---------- K3: replay overflow edges (normally zero) ----------
__global__ void overflow_kernel(const float4* __restrict__ data,
                                const int2* __restrict__ ovf,
                                const int* __restrict__ ovf_count,
                                float* __restrict__ out) {
  int cnt = *ovf_count;
  for (int i = blockIdx.x * blockDim.x + threadIdx.x; i < cnt * 8;
       i += gridDim.x * blockDim.x) {
    int k = i >> 3, q = i & 7;
    int2 ed = ovf[k];
    float4 v = data[(size_t)ed.x * 8 + q];
    float* p = out + (size_t)ed.y * D + q * 4;
    unsafeAtomicAdd(p + 0, v.x * FACTOR);
    unsafeAtomicAdd(p + 1, v.y * FACTOR);
    unsafeAtomicAdd(p + 2, v.z * FACTOR);
    unsafeAtomicAdd(p + 3, v.w * FACTOR);
  }
}

// ---------- Fallback: round-1 atomic scatter ----------
__global__ void atomic_kernel(const float4* __restrict__ edge_data,
                              const int* __restrict__ edge_dst,
                              float* __restrict__ out, int E, int N) {
  int tid = blockIdx.x * blockDim.x + threadIdx.x;
  int e = tid >> 3;
  int q = tid & 7;
  if (e >= E) return;
  int dst = edge_dst[e];
  if (dst < 0 || dst >= N) return;
  float4 v = edge_data[(size_t)e * 8 + q];
  float* p = out + (size_t)dst * D + q * 4;
  unsafeAtomicAdd(p + 0, v.x * FACTOR);
  unsafeAtomicAdd(p + 1, v.y * FACTOR);
  unsafeAtomicAdd(p + 2, v.z * FACTOR);
  unsafeAtomicAdd(p + 3, v.w * FACTOR);
}

extern "C" void kernel_launch(void* const* d_in, const int* in_sizes, int n_in,
                              void* d_out, int out_size, void* d_ws, size_t ws_size,
                              hipStream_t stream) {
  const float4* edge_data = (const float4*)d_in[0];
  const int* edge_dst = (const int*)d_in[1];

  int E = in_sizes[1];
  int N = out_size / D;

  int nb = (N + BNODES - 1) >> BSHIFT;            // 782 for N=100K
  // ws layout (ints): [0..3] ovf_count+pad, [4, 4+nb) cursor,
  // [ofs_order, +nb*CAP) order, then int2 ovf[E].
  size_t ofs_order = 4 + (size_t)nb;
  ofs_order = (ofs_order + 1) & ~(size_t)1;
  size_t ofs_ovf = ofs_order + (size_t)nb * CAP;
  ofs_ovf = (ofs_ovf + 1) & ~(size_t)1;
  size_t need = (ofs_ovf + (size_t)2 * E) * sizeof(int);
  bool pack_ok = ((long long)E << BSHIFT) < (1ll << 31) &&
                 (((long long)nb << CAPSHIFT) < (1ll << 31));

  if (ws_size < need || !pack_ok) {
    float* out = (float*)d_out;
    hipMemsetAsync(d_out, 0, (size_t)out_size * sizeof(float), stream);
    int total = E * 8;
    atomic_kernel<<<(total + 255) / 256, 256, 0, stream>>>(edge_data, edge_dst, out, E, N);
    return;
  }

  int* ws = (int*)d_ws;
  int* ovf_count = ws;
  int* cursor = ws + 4;
  int* order = ws + ofs_order;
  int2* ovf = (int2*)(ws + ofs_ovf);

  init_kernel<<<(nb + 1023) / 1024, 1024, 0, stream>>>(cursor, ovf_count, nb);

  // 128 scatter blocks: per-(block,bucket) region ~ E/(128*nb)*4B ~ 64 B
  // = one cache line -> clean L2 write combining.
  int nblk = 128;
  int chunk = ((E + nblk - 1) / nblk + 3) & ~3;
  size_t lds = (size_t)2 * nb * sizeof(int);
  scatter_kernel<<<nblk, 256, lds, stream>>>(edge_dst, cursor, order, ovf,
                                             ovf_count, E, N, nb, chunk);

  gather_kernel<<<nb, K4_THREADS, 0, stream>>>(
      edge_data, order, cursor, (float4*)d_out, N);

  overflow_kernel<<<32, 256, 0, stream>>>(edge_data, ovf, ovf_count, (float*)d_out);
}

// Round 2
// 328.236 us; speedup vs baseline: 1.0198x; 1.0198x over previous
//
#include <hip/hip_runtime.h>
#include <hip/hip_bf16.h>

// EdgewiseReduce: out[n, :] = sum_{e : dst[e]==n} edge_data[e, :] * 0.5
// E = 1.6M, D = 32, N = 100K.
//
// History:
//  R1: 51.2M f32 global atomics -> 819 MB of 16B txns, 647 us.
//  R2: full counting sort; random 4B scatter -> 106 MB line writebacks, 494.
//  R3: replicated scan -> 1.6 GB L3 traffic, 378 us.
//  R4-R6: LDS-atomic gather stuck 340-464 us.
//  R7: register-accumulating gather + in-LDS bucket sort -> 352 us.
//  R8: fixed-capacity buckets (cap=4096) -> 329.7 us.
//  R9: balanced gather consume -> 334.7 (neutral => gather imbalance was
//      NOT the bottleneck; gather reverted to R8 form).
//  R10 (this): scatter occupancy. Old scatter: 128 blocks x 256 = 1
//      wave/SIMD on half the CUs, latency-bound on LDS atomics + dependent
//      scattered stores, and read dst twice. Now 391 blocks x 512 (8
//      waves/block, all CUs, ~3 waves/SIMD); each thread keeps its 2 int4
//      of dst in REGISTERS across hist+emit passes (one dst read total).
//      Cursor becomes bucket-relative so init collapses to one tiny
//      hipMemsetAsync. Order-write runs shrink 64B->~20B; amplification
//      bounded by ~25 MB (~4 us) vs ~6x scatter TLP.

#define D 32
#define FACTOR 0.5f
#define BSHIFT 7                 // 128 nodes per bucket
#define BNODES (1 << BSHIFT)
#define CAPSHIFT 12              // 4096 slots per bucket
#define CAP (1 << CAPSHIFT)

// ---------- K1: per-block reserve + scatter packed ids ----------
#define S_THREADS 512
#define S_PER_T 2                // int4 per thread -> 8 edges/thread
__global__ __launch_bounds__(S_THREADS)
void scatter_kernel(const int* __restrict__ dst, int* __restrict__ gcursor,
                    int* __restrict__ order, int2* __restrict__ ovf,
                    int* __restrict__ ovf_count, int E, int N, int nb) {
  extern __shared__ int sm[];
  int* lhist = sm;            // [nb]
  int* lcur = sm + nb;        // [nb] absolute scatter cursors
  const int4* dst4 = (const int4*)dst;
  const int n4 = E >> 2;
  const int base4 = blockIdx.x * (S_THREADS * S_PER_T);
  const int i4a = base4 + threadIdx.x;
  const int i4b = i4a + S_THREADS;
  const bool tail_block = (blockIdx.x == gridDim.x - 1);

  for (int i = threadIdx.x; i < nb; i += S_THREADS) lhist[i] = 0;
  __syncthreads();

  // ---- pass A: histogram; dst values stay in registers ----
  int4 va, vb;
  bool ha = (i4a < n4), hb = (i4b < n4);
  if (ha) {
    va = dst4[i4a];
    if ((unsigned)va.x < (unsigned)N) atomicAdd(&lhist[va.x >> BSHIFT], 1);
    if ((unsigned)va.y < (unsigned)N) atomicAdd(&lhist[va.y >> BSHIFT], 1);
    if ((unsigned)va.z < (unsigned)N) atomicAdd(&lhist[va.z >> BSHIFT], 1);
    if ((unsigned)va.w < (unsigned)N) atomicAdd(&lhist[va.w >> BSHIFT], 1);
  }
  if (hb) {
    vb = dst4[i4b];
    if ((unsigned)vb.x < (unsigned)N) atomicAdd(&lhist[vb.x >> BSHIFT], 1);
    if ((unsigned)vb.y < (unsigned)N) atomicAdd(&lhist[vb.y >> BSHIFT], 1);
    if ((unsigned)vb.z < (unsigned)N) atomicAdd(&lhist[vb.z >> BSHIFT], 1);
    if ((unsigned)vb.w < (unsigned)N) atomicAdd(&lhist[vb.w >> BSHIFT], 1);
  }
  if (tail_block) {                       // E % 4 != 0 leftovers (rare)
    for (int e = (n4 << 2) + threadIdx.x; e < E; e += S_THREADS) {
      int d = dst[e];
      if ((unsigned)d < (unsigned)N) atomicAdd(&lhist[d >> BSHIFT], 1);
    }
  }
  __syncthreads();

  // ---- reserve contiguous global runs per bucket ----
  for (int i = threadIdx.x; i < nb; i += S_THREADS) {
    int c = lhist[i];
    lcur[i] = (i << CAPSHIFT) + (c ? atomicAdd(&gcursor[i], c) : 0);
  }
  __syncthreads();

  // ---- pass B: emit packed (edge<<7 | node&127) from registers ----
  #define EMIT(dd, ee)                                                        \
    if ((unsigned)(dd) < (unsigned)N) {                                       \
      int bkt = (dd) >> BSHIFT;                                               \
      int pos = atomicAdd(&lcur[bkt], 1);                                     \
      if (pos < ((bkt + 1) << CAPSHIFT)) {                                    \
        order[pos] = ((ee) << BSHIFT) | ((dd) & (BNODES - 1));                \
      } else {                                                                \
        int op = atomicAdd(ovf_count, 1);                                     \
        ovf[op] = make_int2((ee), (dd));                                      \
      }                                                                       \
    }

  if (ha) {
    int e = i4a << 2;
    EMIT(va.x, e + 0)
    EMIT(va.y, e + 1)
    EMIT(va.z, e + 2)
    EMIT(va.w, e + 3)
  }
  if (hb) {
    int e = i4b << 2;
    EMIT(vb.x, e + 0)
    EMIT(vb.y, e + 1)
    EMIT(vb.z, e + 2)
    EMIT(vb.w, e + 3)
  }
  if (tail_block) {
    for (int e = (n4 << 2) + threadIdx.x; e < E; e += S_THREADS) {
      int d = dst[e];
      EMIT(d, e)
    }
  }
  #undef EMIT
}

// ---------- K2: gather-reduce, register accumulation, 1-wave scan ----------
// 512 threads = 128 groups x 4 lanes; group g owns node (bucket*128 + g).
#define K4_THREADS 512
__global__ __launch_bounds__(K4_THREADS)
void gather_kernel(const float4* __restrict__ data, const int* __restrict__ order,
                   const int* __restrict__ cursor, float4* __restrict__ out,
                   int N) {
  __shared__ int ids[CAP];         // staged bucket ids (16 KB)
  __shared__ int sorted[CAP];      // node-sorted ids (16 KB)
  __shared__ int hist[BNODES];
  __shared__ int offs[BNODES];     // inclusive ends
  __shared__ int cur[BNODES];      // scatter cursors (mutated)

  const int b = blockIdx.x;
  const int base = b << CAPSHIFT;
  int cnt = cursor[b];             // bucket-relative count
  if (cnt > CAP) cnt = CAP;        // overflow handled by overflow_kernel
  if (cnt < 0) cnt = 0;
  const int lo = b << BSHIFT;
  const int tid = threadIdx.x;
  const int grp = tid >> 2;        // node-within-bucket this group owns
  const int ln = tid & 3;          // 32B slice within the 128B row

  for (int i = tid; i < BNODES; i += K4_THREADS) hist[i] = 0;
  __syncthreads();
  for (int i = tid; i < cnt; i += K4_THREADS) {
    int v = order[base + i];
    ids[i] = v;
    atomicAdd(&hist[v & (BNODES - 1)], 1);
  }
  __syncthreads();

  // Single-wave inclusive scan over 128 counters (lane l owns 2l, 2l+1).
  if (tid < 64) {
    int c0 = hist[2 * tid], c1 = hist[2 * tid + 1];
    int s = c0 + c1;
    int sc = s;
    #pragma unroll
    for (int off = 1; off < 64; off <<= 1) {
      int t = __shfl_up(sc, off);
      if (tid >= off) sc += t;
    }
    int bs = sc - s;                 // exclusive base for node 2*tid
    offs[2 * tid] = bs + c0;         // inclusive end of node 2*tid
    offs[2 * tid + 1] = bs + c0 + c1;
    cur[2 * tid] = bs;
    cur[2 * tid + 1] = bs + c0;
  }
  __syncthreads();

  for (int i = tid; i < cnt; i += K4_THREADS) {
    int v = ids[i];
    sorted[atomicAdd(&cur[v & (BNODES - 1)], 1)] = v;
  }
  __syncthreads();

  // Consume this group's contiguous sublist; 4-id unroll (8 loads live).
  float4 acc0 = make_float4(0.f, 0.f, 0.f, 0.f);
  float4 acc1 = make_float4(0.f, 0.f, 0.f, 0.f);
  int e_ = offs[grp];
  int i = e_ - hist[grp];
  for (; i + 3 < e_; i += 4) {
    int r0 = sorted[i] >> BSHIFT;
    int r1 = sorted[i + 1] >> BSHIFT;
    int r2 = sorted[i + 2] >> BSHIFT;
    int r3 = sorted[i + 3] >> BSHIFT;
    const float4* p0 = data + (size_t)r0 * 8 + ln * 2;
    const float4* p1 = data + (size_t)r1 * 8 + ln * 2;
    const float4* p2 = data + (size_t)r2 * 8 + ln * 2;
    const float4* p3 = data + (size_t)r3 * 8 + ln * 2;
    float4 x0 = p0[0], y0 = p0[1];
    float4 x1 = p1[0], y1 = p1[1];
    float4 x2 = p2[0], y2 = p2[1];
    float4 x3 = p3[0], y3 = p3[1];
    acc0.x += x0.x + x1.x + x2.x + x3.x;
    acc0.y += x0.y + x1.y + x2.y + x3.y;
    acc0.z += x0.z + x1.z + x2.z + x3.z;
    acc0.w += x0.w + x1.w + x2.w + x3.w;
    acc1.x += y0.x + y1.x + y2.x + y3.x;
    acc1.y += y0.y + y1.y + y2.y + y3.y;
    acc1.z += y0.z + y1.z + y2.z + y3.z;
    acc1.w += y0.w + y1.w + y2.w + y3.w;
  }
  for (; i < e_; ++i) {
    int r0 = sorted[i] >> BSHIFT;
    const float4* p0 = data + (size_t)r0 * 8 + ln * 2;
    float4 x0 = p0[0], y0 = p0[1];
    acc0.x += x0.x; acc0.y += x0.y; acc0.z += x0.z; acc0.w += x0.w;
    acc1.x += y0.x; acc1.y += y0.y; acc1.z += y0.z; acc1.w += y0.w;
  }

  int node = lo + grp;
  if (node < N) {
    float4 o0, o1;
    o0.x = acc0.x * FACTOR; o0.y = acc0.y * FACTOR;
    o0.z = acc0.z * FACTOR; o0.w = acc0.w * FACTOR;
    o1.x = acc1.x * FACTOR; o1.y = acc1.y * FACTOR;
    o1.z = acc1.z * FACTOR; o1.w = acc1.w * FACTOR;
    out[(size_t)node * 8 + ln * 2] = o0;
    out[(size_t)node * 8 + ln * 2 + 1] = o1;
  }
}

// ---------- K3: replay overflow edges (normally zero) ----------
__global__ void overflow_kernel(const float4* __restrict__ data,
                                const int2* __restrict__ ovf,
                                const int* __restrict__ ovf_count,
                                float* __restrict__ out) {
  int cnt = *ovf_count;
  for (int i = blockIdx.x * blockDim.x + threadIdx.x; i < cnt * 8;
       i += gridDim.x * blockDim.x) {
    int k = i >> 3, q = i & 7;
    int2 ed = ovf[k];
    float4 v = data[(size_t)ed.x * 8 + q];
    float* p = out + (size_t)ed.y * D + q * 4;
    unsafeAtomicAdd(p + 0, v.x * FACTOR);
    unsafeAtomicAdd(p + 1, v.y * FACTOR);
    unsafeAtomicAdd(p + 2, v.z * FACTOR);
    unsafeAtomicAdd(p + 3, v.w * FACTOR);
  }
}

// ---------- Fallback: round-1 atomic scatter ----------
__global__ void atomic_kernel(const float4* __restrict__ edge_data,
                              const int* __restrict__ edge_dst,
                              float* __restrict__ out, int E, int N) {
  int tid = blockIdx.x * blockDim.x + threadIdx.x;
  int e = tid >> 3;
  int q = tid & 7;
  if (e >= E) return;
  int dst = edge_dst[e];
  if (dst < 0 || dst >= N) return;
  float4 v = edge_data[(size_t)e * 8 + q];
  float* p = out + (size_t)dst * D + q * 4;
  unsafeAtomicAdd(p + 0, v.x * FACTOR);
  unsafeAtomicAdd(p + 1, v.y * FACTOR);
  unsafeAtomicAdd(p + 2, v.z * FACTOR);
  unsafeAtomicAdd(p + 3, v.w * FACTOR);
}

extern "C" void kernel_launch(void* const* d_in, const int* in_sizes, int n_in,
                              void* d_out, int out_size, void* d_ws, size_t ws_size,
                              hipStream_t stream) {
  const float4* edge_data = (const float4*)d_in[0];
  const int* edge_dst = (const int*)d_in[1];

  int E = in_sizes[1];
  int N = out_size / D;

  int nb = (N + BNODES - 1) >> BSHIFT;            // 782 for N=100K
  // ws layout (ints): [0..3] ovf_count+pad, [4, 4+nb) cursor,
  // [ofs_order, +nb*CAP) order, then int2 ovf[E].
  size_t ofs_order = 4 + (size_t)nb;
  ofs_order = (ofs_order + 1) & ~(size_t)1;
  size_t ofs_ovf = ofs_order + (size_t)nb * CAP;
  ofs_ovf = (ofs_ovf + 1) & ~(size_t)1;
  size_t need = (ofs_ovf + (size_t)2 * E) * sizeof(int);
  bool pack_ok = ((long long)E << BSHIFT) < (1ll << 31) &&
                 (((long long)nb << CAPSHIFT) < (1ll << 31));

  if (ws_size < need || !pack_ok) {
    float* out = (float*)d_out;
    hipMemsetAsync(d_out, 0, (size_t)out_size * sizeof(float), stream);
    int total = E * 8;
    atomic_kernel<<<(total + 255) / 256, 256, 0, stream>>>(edge_data, edge_dst, out, E, N);
    return;
  }

  int* ws = (int*)d_ws;
  int* ovf_count = ws;
  int* cursor = ws + 4;
  int* order = ws + ofs_order;
  int2* ovf = (int2*)(ws + ofs_ovf);

  // Zero ovf_count + bucket-relative cursors in one tiny fill.
  hipMemsetAsync(ws, 0, (4 + (size_t)nb) * sizeof(int), stream);

  // Scatter: 8 edges/thread held in registers; ~391 blocks x 8 waves
  // covers all 256 CUs at ~3 waves/SIMD (old: 1 wave/SIMD on 128 CUs).
  int epb = S_THREADS * S_PER_T * 4;              // edges per block (4096)
  int nblk = (E + epb - 1) / epb;
  if (nblk < 1) nblk = 1;
  size_t lds = (size_t)2 * nb * sizeof(int);
  scatter_kernel<<<nblk, S_THREADS, lds, stream>>>(edge_dst, cursor, order, ovf,
                                                   ovf_count, E, N, nb);

  gather_kernel<<<nb, K4_THREADS, 0, stream>>>(
      edge_data, order, cursor, (float4*)d_out, N);

  overflow_kernel<<<32, 256, 0, stream>>>(edge_data, ovf, ovf_count, (float*)d_out);
}

// Round 5
// 316.412 us; speedup vs baseline: 1.0579x; 1.0374x over previous
//
#include <hip/hip_runtime.h>
#include <hip/hip_bf16.h>

// EdgewiseReduce: out[n, :] = sum_{e : dst[e]==n} edge_data[e, :] * 0.5
// E = 1.6M, D = 32, N = 100K.
//
// History:
//  R1: 51.2M f32 global atomics -> 819 MB of 16B txns, 647 us.
//  R2: full counting sort; random 4B scatter -> 106 MB line writebacks, 494.
//  R3: replicated scan -> 1.6 GB L3 traffic, 378 us.
//  R4-R6: LDS-atomic gather stuck 340-464 us.
//  R7: register-accumulating gather + in-LDS bucket sort -> 352 us.
//  R8: fixed-capacity buckets (cap=4096) -> 329.7 us.
//  R9: balanced gather consume -> 334.7 (neutral).
//  R10: scatter occupancy 128x256 -> 391x512, dst in regs -> 328.2 (neutral).
//      rocprof top-5 every round = 800 MB fillBufferAligned dispatches
//      (~120us each) — harness workspace re-poison inside the measured
//      graph. Bottom-up kernel model (scatter ~20, gather ~60, misc ~8)
//      fits dur_us - 2*fill.
//  R11: scatter local counting sort + run-coalesced emit + NT hints.
//      Container infra died (no data).
//  R12: resubmit; compile error — __builtin_nontemporal_* rejects
//      HIP_vector_type<float,4>*; needs native ext_vector_type pointer.
//  R13 (this): same experiment, NT helpers fixed via f32x4 ext_vector
//      round-trip (layout-identical to float4). Pre-committed: neutral
//      (+-2%) => fill-dominated model confirmed => ROOFLINE.

#define D 32
#define FACTOR 0.5f
#define BSHIFT 7                 // 128 nodes per bucket
#define BNODES (1 << BSHIFT)
#define CAPSHIFT 12              // 4096 slots per bucket
#define CAP (1 << CAPSHIFT)

typedef float f32x4 __attribute__((ext_vector_type(4)));

__device__ __forceinline__ float4 ntload(const float4* p) {
  f32x4 v = __builtin_nontemporal_load((const f32x4*)p);
  return make_float4(v.x, v.y, v.z, v.w);
}
__device__ __forceinline__ void ntstore(float4* p, float4 v) {
  f32x4 t;
  t.x = v.x; t.y = v.y; t.z = v.z; t.w = v.w;
  __builtin_nontemporal_store(t, (f32x4*)p);
}

// ---------- K1: hist -> reserve -> local sort -> coalesced emit ----------
#define S_THREADS 512
#define S_PER_T 2                // int4 per thread -> 8 edges/thread
#define S_EDGES (S_THREADS * S_PER_T * 4)   // 4096 edges per block
__global__ __launch_bounds__(S_THREADS)
void scatter_kernel(const int* __restrict__ dst, int* __restrict__ gcursor,
                    int* __restrict__ order, int2* __restrict__ ovf,
                    int* __restrict__ ovf_count, int E, int N, int nb) {
  extern __shared__ int sm[];
  int* lhist = sm;                 // [nb] block-local bucket counts
  int* lstart = sm + nb;           // [nb] exclusive local scan
  int* lcur = sm + 2 * nb;         // [nb] local rank cursors
  int* grun = sm + 3 * nb;         // [nb] reserved global (bucket-rel) start
  int* staging = sm + 4 * nb;      // [S_EDGES] locally sorted packed ids
  short* sbkt = (short*)(staging + S_EDGES);  // [S_EDGES] bucket of slot

  const int4* dst4 = (const int4*)dst;
  const int n4 = E >> 2;
  const int base4 = blockIdx.x * (S_THREADS * S_PER_T);
  const int i4a = base4 + threadIdx.x;
  const int i4b = i4a + S_THREADS;
  const bool tail_block = (blockIdx.x == gridDim.x - 1);
  const int tid = threadIdx.x;

  for (int i = tid; i < nb; i += S_THREADS) { lhist[i] = 0; lcur[i] = 0; }
  __syncthreads();

  // ---- pass A: histogram; dst values stay in registers ----
  int4 va, vb;
  bool ha = (i4a < n4), hb = (i4b < n4);
  if (ha) {
    va = dst4[i4a];
    if ((unsigned)va.x < (unsigned)N) atomicAdd(&lhist[va.x >> BSHIFT], 1);
    if ((unsigned)va.y < (unsigned)N) atomicAdd(&lhist[va.y >> BSHIFT], 1);
    if ((unsigned)va.z < (unsigned)N) atomicAdd(&lhist[va.z >> BSHIFT], 1);
    if ((unsigned)va.w < (unsigned)N) atomicAdd(&lhist[va.w >> BSHIFT], 1);
  }
  if (hb) {
    vb = dst4[i4b];
    if ((unsigned)vb.x < (unsigned)N) atomicAdd(&lhist[vb.x >> BSHIFT], 1);
    if ((unsigned)vb.y < (unsigned)N) atomicAdd(&lhist[vb.y >> BSHIFT], 1);
    if ((unsigned)vb.z < (unsigned)N) atomicAdd(&lhist[vb.z >> BSHIFT], 1);
    if ((unsigned)vb.w < (unsigned)N) atomicAdd(&lhist[vb.w >> BSHIFT], 1);
  }
  if (tail_block) {                       // E % 4 != 0 leftovers (rare)
    for (int e = (n4 << 2) + tid; e < E; e += S_THREADS) {
      int d = dst[e];
      if ((unsigned)d < (unsigned)N) atomicAdd(&lhist[d >> BSHIFT], 1);
    }
  }
  __syncthreads();

  // ---- reserve global runs + local exclusive scan (wave 0) ----
  for (int i = tid; i < nb; i += S_THREADS) {
    int c = lhist[i];
    grun[i] = c ? atomicAdd(&gcursor[i], c) : 0;   // bucket-relative
  }
  if (tid < 64) {
    int carry = 0;
    int nchunk = (nb + 63) >> 6;
    for (int c = 0; c < nchunk; ++c) {
      int idx = (c << 6) + tid;
      int v = (idx < nb) ? lhist[idx] : 0;
      int sc = v;
      #pragma unroll
      for (int off = 1; off < 64; off <<= 1) {
        int t = __shfl_up(sc, off);
        if (tid >= off) sc += t;
      }
      if (idx < nb) lstart[idx] = carry + sc - v;
      carry += __shfl(sc, 63);
    }
  }
  __syncthreads();

  // ---- pass B: rank + stage into locally sorted order ----
  #define STAGE(dd, ee)                                                       \
    if ((unsigned)(dd) < (unsigned)N) {                                       \
      int bkt = (dd) >> BSHIFT;                                               \
      int rank = atomicAdd(&lcur[bkt], 1);                                    \
      int s = lstart[bkt] + rank;                                             \
      if (s < S_EDGES) {                                                      \
        staging[s] = ((ee) << BSHIFT) | ((dd) & (BNODES - 1));                \
        sbkt[s] = (short)bkt;                                                 \
      }                                                                       \
    }

  if (ha) {
    int e = i4a << 2;
    STAGE(va.x, e + 0)
    STAGE(va.y, e + 1)
    STAGE(va.z, e + 2)
    STAGE(va.w, e + 3)
  }
  if (hb) {
    int e = i4b << 2;
    STAGE(vb.x, e + 0)
    STAGE(vb.y, e + 1)
    STAGE(vb.z, e + 2)
    STAGE(vb.w, e + 3)
  }
  if (tail_block) {
    for (int e = (n4 << 2) + tid; e < E; e += S_THREADS) {
      int d = dst[e];
      STAGE(d, e)
    }
  }
  #undef STAGE
  __syncthreads();

  // ---- pass C: coalesced emit. Consecutive tids -> consecutive slots ->
  //      consecutive global dests within each bucket run. ----
  int tot = lstart[nb - 1] + lhist[nb - 1];
  if (tot > S_EDGES) tot = S_EDGES;
  for (int s = tid; s < tot; s += S_THREADS) {
    int v = staging[s];
    int bkt = sbkt[s];
    int grel = grun[bkt] + (s - lstart[bkt]);
    if (grel < CAP) {
      order[((size_t)bkt << CAPSHIFT) + grel] = v;
    } else {
      int op = atomicAdd(ovf_count, 1);
      ovf[op] = make_int2(v >> BSHIFT, (bkt << BSHIFT) | (v & (BNODES - 1)));
    }
  }
}

// ---------- K2: gather-reduce, register accumulation, 1-wave scan ----------
// 512 threads = 128 groups x 4 lanes; group g owns node (bucket*128 + g).
#define K4_THREADS 512
__global__ __launch_bounds__(K4_THREADS)
void gather_kernel(const float4* __restrict__ data, const int* __restrict__ order,
                   const int* __restrict__ cursor, float4* __restrict__ out,
                   int N) {
  __shared__ int ids[CAP];         // staged bucket ids (16 KB)
  __shared__ int sorted[CAP];      // node-sorted ids (16 KB)
  __shared__ int hist[BNODES];
  __shared__ int offs[BNODES];     // inclusive ends
  __shared__ int cur[BNODES];      // scatter cursors (mutated)

  const int b = blockIdx.x;
  const int base = b << CAPSHIFT;
  int cnt = cursor[b];             // bucket-relative count
  if (cnt > CAP) cnt = CAP;        // overflow handled by overflow_kernel
  if (cnt < 0) cnt = 0;
  const int lo = b << BSHIFT;
  const int tid = threadIdx.x;
  const int grp = tid >> 2;        // node-within-bucket this group owns
  const int ln = tid & 3;          // 32B slice within the 128B row

  for (int i = tid; i < BNODES; i += K4_THREADS) hist[i] = 0;
  __syncthreads();
  for (int i = tid; i < cnt; i += K4_THREADS) {
    int v = order[base + i];
    ids[i] = v;
    atomicAdd(&hist[v & (BNODES - 1)], 1);
  }
  __syncthreads();

  // Single-wave inclusive scan over 128 counters (lane l owns 2l, 2l+1).
  if (tid < 64) {
    int c0 = hist[2 * tid], c1 = hist[2 * tid + 1];
    int s = c0 + c1;
    int sc = s;
    #pragma unroll
    for (int off = 1; off < 64; off <<= 1) {
      int t = __shfl_up(sc, off);
      if (tid >= off) sc += t;
    }
    int bs = sc - s;                 // exclusive base for node 2*tid
    offs[2 * tid] = bs + c0;         // inclusive end of node 2*tid
    offs[2 * tid + 1] = bs + c0 + c1;
    cur[2 * tid] = bs;
    cur[2 * tid + 1] = bs + c0;
  }
  __syncthreads();

  for (int i = tid; i < cnt; i += K4_THREADS) {
    int v = ids[i];
    sorted[atomicAdd(&cur[v & (BNODES - 1)], 1)] = v;
  }
  __syncthreads();

  // Consume this group's contiguous sublist; 4-id unroll (8 loads live).
  float4 acc0 = make_float4(0.f, 0.f, 0.f, 0.f);
  float4 acc1 = make_float4(0.f, 0.f, 0.f, 0.f);
  int e_ = offs[grp];
  int i = e_ - hist[grp];
  for (; i + 3 < e_; i += 4) {
    int r0 = sorted[i] >> BSHIFT;
    int r1 = sorted[i + 1] >> BSHIFT;
    int r2 = sorted[i + 2] >> BSHIFT;
    int r3 = sorted[i + 3] >> BSHIFT;
    const float4* p0 = data + (size_t)r0 * 8 + ln * 2;
    const float4* p1 = data + (size_t)r1 * 8 + ln * 2;
    const float4* p2 = data + (size_t)r2 * 8 + ln * 2;
    const float4* p3 = data + (size_t)r3 * 8 + ln * 2;
    float4 x0 = ntload(p0), y0 = ntload(p0 + 1);
    float4 x1 = ntload(p1), y1 = ntload(p1 + 1);
    float4 x2 = ntload(p2), y2 = ntload(p2 + 1);
    float4 x3 = ntload(p3), y3 = ntload(p3 + 1);
    acc0.x += x0.x + x1.x + x2.x + x3.x;
    acc0.y += x0.y + x1.y + x2.y + x3.y;
    acc0.z += x0.z + x1.z + x2.z + x3.z;
    acc0.w += x0.w + x1.w + x2.w + x3.w;
    acc1.x += y0.x + y1.x + y2.x + y3.x;
    acc1.y += y0.y + y1.y + y2.y + y3.y;
    acc1.z += y0.z + y1.z + y2.z + y3.z;
    acc1.w += y0.w + y1.w + y2.w + y3.w;
  }
  for (; i < e_; ++i) {
    int r0 = sorted[i] >> BSHIFT;
    const float4* p0 = data + (size_t)r0 * 8 + ln * 2;
    float4 x0 = ntload(p0), y0 = ntload(p0 + 1);
    acc0.x += x0.x; acc0.y += x0.y; acc0.z += x0.z; acc0.w += x0.w;
    acc1.x += y0.x; acc1.y += y0.y; acc1.z += y0.z; acc1.w += y0.w;
  }

  int node = lo + grp;
  if (node < N) {
    float4 o0, o1;
    o0.x = acc0.x * FACTOR; o0.y = acc0.y * FACTOR;
    o0.z = acc0.z * FACTOR; o0.w = acc0.w * FACTOR;
    o1.x = acc1.x * FACTOR; o1.y = acc1.y * FACTOR;
    o1.z = acc1.z * FACTOR; o1.w = acc1.w * FACTOR;
    ntstore(out + (size_t)node * 8 + ln * 2, o0);
    ntstore(out + (size_t)node * 8 + ln * 2 + 1, o1);
  }
}

// ---------- K3: replay overflow edges (normally zero) ----------
__global__ void overflow_kernel(const float4* __restrict__ data,
                                const int2* __restrict__ ovf,
                                const int* __restrict__ ovf_count,
                                float* __restrict__ out) {
  int cnt = *ovf_count;
  for (int i = blockIdx.x * blockDim.x + threadIdx.x; i < cnt * 8;
       i += gridDim.x * blockDim.x) {
    int k = i >> 3, q = i & 7;
    int2 ed = ovf[k];
    float4 v = data[(size_t)ed.x * 8 + q];
    float* p = out + (size_t)ed.y * D + q * 4;
    unsafeAtomicAdd(p + 0, v.x * FACTOR);
    unsafeAtomicAdd(p + 1, v.y * FACTOR);
    unsafeAtomicAdd(p + 2, v.z * FACTOR);
    unsafeAtomicAdd(p + 3, v.w * FACTOR);
  }
}

// ---------- Fallback: round-1 atomic scatter ----------
__global__ void atomic_kernel(const float4* __restrict__ edge_data,
                              const int* __restrict__ edge_dst,
                              float* __restrict__ out, int E, int N) {
  int tid = blockIdx.x * blockDim.x + threadIdx.x;
  int e = tid >> 3;
  int q = tid & 7;
  if (e >= E) return;
  int dst = edge_dst[e];
  if (dst < 0 || dst >= N) return;
  float4 v = edge_data[(size_t)e * 8 + q];
  float* p = out + (size_t)dst * D + q * 4;
  unsafeAtomicAdd(p + 0, v.x * FACTOR);
  unsafeAtomicAdd(p + 1, v.y * FACTOR);
  unsafeAtomicAdd(p + 2, v.z * FACTOR);
  unsafeAtomicAdd(p + 3, v.w * FACTOR);
}

extern "C" void kernel_launch(void* const* d_in, const int* in_sizes, int n_in,
                              void* d_out, int out_size, void* d_ws, size_t ws_size,
                              hipStream_t stream) {
  const float4* edge_data = (const float4*)d_in[0];
  const int* edge_dst = (const int*)d_in[1];

  int E = in_sizes[1];
  int N = out_size / D;

  int nb = (N + BNODES - 1) >> BSHIFT;            // 782 for N=100K
  // ws layout (ints): [0..3] ovf_count+pad, [4, 4+nb) cursor,
  // [ofs_order, +nb*CAP) order, then int2 ovf[E].
  size_t ofs_order = 4 + (size_t)nb;
  ofs_order = (ofs_order + 1) & ~(size_t)1;
  size_t ofs_ovf = ofs_order + (size_t)nb * CAP;
  ofs_ovf = (ofs_ovf + 1) & ~(size_t)1;
  size_t need = (ofs_ovf + (size_t)2 * E) * sizeof(int);
  bool pack_ok = ((long long)E << BSHIFT) < (1ll << 31) &&
                 (((long long)nb << CAPSHIFT) < (1ll << 31));
  // Scatter LDS: 4*nb ints + staging 4096 ints + sbkt 4096 shorts.
  size_t s_lds = (size_t)4 * nb * sizeof(int) + S_EDGES * sizeof(int) +
                 S_EDGES * sizeof(short);
  bool lds_ok = s_lds <= 64 * 1024 && nb > 0;

  if (ws_size < need || !pack_ok || !lds_ok) {
    float* out = (float*)d_out;
    (void)hipMemsetAsync(d_out, 0, (size_t)out_size * sizeof(float), stream);
    int total = E * 8;
    atomic_kernel<<<(total + 255) / 256, 256, 0, stream>>>(edge_data, edge_dst, out, E, N);
    return;
  }

  int* ws = (int*)d_ws;
  int* ovf_count = ws;
  int* cursor = ws + 4;
  int* order = ws + ofs_order;
  int2* ovf = (int2*)(ws + ofs_ovf);

  // Zero ovf_count + bucket-relative cursors in one tiny fill.
  (void)hipMemsetAsync(ws, 0, (4 + (size_t)nb) * sizeof(int), stream);

  int nblk = (E + S_EDGES - 1) / S_EDGES;
  if (nblk < 1) nblk = 1;
  scatter_kernel<<<nblk, S_THREADS, s_lds, stream>>>(edge_dst, cursor, order, ovf,
                                                     ovf_count, E, N, nb);

  gather_kernel<<<nb, K4_THREADS, 0, stream>>>(
      edge_data, order, cursor, (float4*)d_out, N);

  overflow_kernel<<<32, 256, 0, stream>>>(edge_data, ovf, ovf_count, (float*)d_out);
}